// Round 13
// baseline (295.248 us; speedup 1.0000x reference)
//
#include <hip/hip_runtime.h>
#include <hip/hip_bf16.h>
#include <stdint.h>

// Problem constants
#define OUT_DIM 4096
#define IN_DIM  4096
#define GROUPSZ 128
#define NGROUPS 32
#define M_TOTAL 8192   // 4 * 2048
#define EPS_Q   1e-12f

// GEMM tiling: 256x256 tile, BK=32, 8 waves (2M x 4N), 16x16x32 MFMA
// BOTH operands in 4-deep LDS rings; 1 barrier + 1 counted vmcnt per K-tile.
#define BM 256
#define BN 256
#define BK 32
#define NT (IN_DIM / BK)   // 128 K-tiles

typedef float f32x4   __attribute__((ext_vector_type(4)));
typedef float float4v __attribute__((ext_vector_type(4)));
typedef short bf16x8  __attribute__((ext_vector_type(8)));

static __device__ __forceinline__ short f2bf(float f) {
    union { float f; unsigned u; } v; v.f = f;
    unsigned r = v.u + 0x7fffu + ((v.u >> 16) & 1u);
    return (short)(r >> 16);
}

#define GLOAD16(gp, lp) __builtin_amdgcn_global_load_lds( \
    (const __attribute__((address_space(1))) void*)(gp),  \
    (__attribute__((address_space(3))) void*)(lp), 16, 0, 0)

// ---------------------------------------------------------------------------
// Kernel 1: dequantize W (bf16, [N][K] = B^T layout). One wave per (o, g).
// ---------------------------------------------------------------------------
__global__ __launch_bounds__(256) void dequant_kernel(
    const float* __restrict__ norms_p, const float* __restrict__ norms_r,
    const int* __restrict__ idx_p, const int* __restrict__ idx_r,
    short* __restrict__ W)
{
    const int gid  = (int)((blockIdx.x * 256u + threadIdx.x) >> 6);
    const int lane = threadIdx.x & 63;
    const size_t base = (size_t)gid * GROUPSZ;

    const int ip0 = idx_p[base + lane];
    const int ip1 = idx_p[base + lane + 64];
    const int ir0 = idx_r[base + lane];
    const int ir1 = idx_r[base + lane + 64];

    const float qp0 = -1.f + (2.f / 15.f) * (float)ip0;
    const float qp1 = -1.f + (2.f / 15.f) * (float)ip1;
    const float qr0 = -1.f + (2.f / 3.f)  * (float)ir0;
    const float qr1 = -1.f + (2.f / 3.f)  * (float)ir1;

    float ssp = qp0 * qp0 + qp1 * qp1;
    float ssr = qr0 * qr0 + qr1 * qr1;
    #pragma unroll
    for (int m = 32; m >= 1; m >>= 1) {
        ssp += __shfl_xor(ssp, m);
        ssr += __shfl_xor(ssr, m);
    }
    const float sp = norms_p[gid] / sqrtf(ssp + EPS_Q);
    const float sr = norms_r[gid] / sqrtf(ssr + EPS_Q);

    W[base + lane]      = f2bf(qp0 * sp + qr0 * sr);
    W[base + lane + 64] = f2bf(qp1 * sp + qr1 * sr);
}

// ---------------------------------------------------------------------------
// Kernel 2: x fp32 -> bf16, 8 elems/thread
// ---------------------------------------------------------------------------
__global__ __launch_bounds__(256) void cast_kernel(
    const float* __restrict__ x, short* __restrict__ xb)
{
    const size_t i = ((size_t)blockIdx.x * 256u + threadIdx.x) * 8u;
    float4v a = *(const float4v*)(x + i);
    float4v b = *(const float4v*)(x + i + 4);
    bf16x8 o;
    o[0] = f2bf(a[0]); o[1] = f2bf(a[1]); o[2] = f2bf(a[2]); o[3] = f2bf(a[3]);
    o[4] = f2bf(b[0]); o[5] = f2bf(b[1]); o[6] = f2bf(b[2]); o[7] = f2bf(b[3]);
    *(bf16x8*)(xb + i) = o;
}

// ---------------------------------------------------------------------------
// GEMM helpers (compile-time indexed everywhere — rule #20)
// ---------------------------------------------------------------------------
template<int HA, int HB>
__device__ __forceinline__ void mfma_quad(f32x4 (&acc)[2][2][4][2],
                                          const bf16x8 (&a)[4],
                                          const bf16x8 (&b)[2]) {
#pragma unroll
    for (int m = 0; m < 4; ++m)
#pragma unroll
        for (int n = 0; n < 2; ++n)
            acc[HA][HB][m][n] = __builtin_amdgcn_mfma_f32_16x16x32_bf16(
                a[m], b[n], acc[HA][HB][m][n], 0, 0, 0);
}

static __device__ __forceinline__ void rdA4(const short* base, int ck,
                                            bf16x8 (&f)[4]) {
#pragma unroll
    for (int m = 0; m < 4; ++m)
        f[m] = *(const bf16x8*)(base + m * 512 + ck);   // 16 rows * 32 cols
}

static __device__ __forceinline__ void rdB2(const short* base, int ck,
                                            bf16x8 (&f)[2]) {
#pragma unroll
    for (int n = 0; n < 2; ++n)
        f[n] = *(const bf16x8*)(base + n * 512 + ck);
}

#define BARRIER()  asm volatile("s_barrier" ::: "memory")
#define SCHEDBAR() __builtin_amdgcn_sched_barrier(0)
#define LGKMC(N)   do { asm volatile("s_waitcnt lgkmcnt(" #N ")" ::: "memory"); \
                        SCHEDBAR(); } while (0)
#define WAITV(N)   asm volatile("s_waitcnt vmcnt(" #N ")" ::: "memory")
#define PRIO1()    __builtin_amdgcn_s_setprio(1)
#define PRIO0()    __builtin_amdgcn_s_setprio(0)

// ---------------------------------------------------------------------------
// Kernel 3: C[M][N] = A[M][K] @ B[N][K]^T + bias, bf16 in / fp32 out.
// BK=32, 4-deep LDS rings for A and B (4 x (16+16) KiB = 128 KiB), staged
// 3 tiles ahead; ONE barrier + ONE counted vmcnt per K-tile (at tile end,
// never mid-compute). Deferred quad(1,1) of t-1 covers the read burst.
//
// Per tile t (steady):
//   rd af(4), bf0(2); stageA(t+3), stageB(t+3) [4 vm];
//   SCHEDBAR; [PEND quad(1,1) of t-1 — old af2/bf1 regs];
//   rd bf1(2); SCHEDBAR; rd af2(4);
//   LGKMC(6) -> quad(0,0);  LGKMC(4) -> quad(0,1);  LGKMC(0) -> quad(1,0);
//   WAITV(8) [drains tile t+1's 4 loads]; BARRIER.
// Ledger: entering t outstanding = [t+1(4), t+2(4)]; +4 issued; WAITV(8).
// Tails: NT-3 WAITV(4), NT-2 WAITV(0), NT-1 bare + inline quad(1,1).
// WAR: stage(t+3) writes ring slot (t-1)&3; all waves' reads of it finished
// (per-wave LGKMC(0) before quad(1,0)) before the entry barrier of tile t.
//
// Swizzle (2-bit): LDS[r][c] holds global chunk c ^ swz(r),
// swz(r) = (r ^ (r>>2)) & 3. Fragment read chunk = lq ^ ((fr ^ (fr>>2))&3)
// -> every 16-lane phase group covers 4 distinct chunk-quads (bank-clean);
// the plain (r&3) version would 4-way conflict on lanes {0,4,8,12}.
// LDS: A slots [0,32768): slot*8192; B slots [32768,65536): +slot*8192.
// Slot = 256 rows x 32 cols; +128 rows = +4096 shorts (A-half1 / B-half1).
// ---------------------------------------------------------------------------
__global__ __launch_bounds__(512, 2) void gemm_kernel(
    const short* __restrict__ Ag,  // [M][K] bf16
    const short* __restrict__ Bg,  // [N][K] bf16
    const float* __restrict__ bias,
    float* __restrict__ C)
{
    __shared__ short lds[65536];   // 128 KiB

    const int tid  = threadIdx.x;
    const int lane = tid & 63;
    const int wid  = tid >> 6;     // 0..7
    const int wr   = wid >> 2;     // 0..1 (M)
    const int wc   = wid & 3;      // 0..3 (N)
    const int fr   = lane & 15;
    const int lq   = lane >> 4;    // 0..3

    // bijective XCD swizzle (nwg = 512, divisible by 8)
    const int nwg = gridDim.x;
    const int cpx = nwg >> 3;
    const int wg  = ((int)blockIdx.x & 7) * cpx + ((int)blockIdx.x >> 3);
    const int ntile = wg & 15;              // N/BN = 16
    const int mtile = wg >> 4;              // M/BM = 32
    const uint32_t brow = (uint32_t)mtile * BM;
    const uint32_t bcol = (uint32_t)ntile * BN;

    // staging: thread owns slot-indices tid (rows 0..127) and tid+512
    // (rows 128..255); r = tid>>2 (+128), c = tid&3.
    // global chunk = c ^ swz(r); swz(r) = (r ^ (r>>2)) & 3, identical for
    // both owned rows (r and r+128).
    const uint32_t sr_ = (uint32_t)(tid >> 2);
    const uint32_t gc_ = (uint32_t)((tid & 3) ^ ((tid >> 2) & 3) ^ ((tid >> 4) & 3));
    const uint32_t aOff = (brow + sr_) * IN_DIM + gc_ * 8;
    const uint32_t bOff = (bcol + sr_) * IN_DIM + gc_ * 8;

    auto stageA = [&](int t) {
        short* dst = lds + (t & 3) * 8192;
        const short* src = Ag + aOff + (uint32_t)t * 32u;
        GLOAD16(src,           dst + tid * 8);
        GLOAD16(src + 524288u, dst + tid * 8 + 4096);   // +128 rows
    };
    auto stageB = [&](int t) {
        short* dst = lds + 32768 + (t & 3) * 8192;
        const short* src = Bg + bOff + (uint32_t)t * 32u;
        GLOAD16(src,           dst + tid * 8);
        GLOAD16(src + 524288u, dst + tid * 8 + 4096);
    };

    // fragment read offsets (shorts): row*32 + chunk*8,
    // chunk = lq ^ ((fr ^ (fr>>2)) & 3); row offsets are multiples of 16.
    const int ck  = (lq ^ ((fr ^ (fr >> 2)) & 3)) * 8;
    const int aRd = (wr * 64 + fr) * 32;
    const int bRd = (wc * 32 + fr) * 32;

    f32x4  acc[2][2][4][2] = {};
    bf16x8 af[4], af2[4], bf0[2], bf1[2];

    // prologue: tiles 0,1,2 staged (12 loads)
    stageA(0); stageB(0);
    stageA(1); stageB(1);
    stageA(2); stageB(2);
    SCHEDBAR();
    WAITV(8);          // tile 0 landed; outstanding [t1(4), t2(4)]
    BARRIER();

#define TILE(T, PEND, STG, WAIT_END, BAR_END, DO_TAIL) do {                   \
    const short* sa = lds + ((T) & 3) * 8192;                                 \
    const short* sbv = lds + 32768 + ((T) & 3) * 8192;                        \
    rdA4(sa + aRd, ck, af);                                                   \
    rdB2(sbv + bRd, ck, bf0);                                                 \
    if (STG) { stageA((T) + 3); stageB((T) + 3); }                            \
    SCHEDBAR();                                                               \
    if (PEND) { PRIO1(); mfma_quad<1,1>(acc, af2, bf1); PRIO0(); }            \
    rdB2(sbv + 4096 + bRd, ck, bf1);                                          \
    SCHEDBAR();                                                               \
    rdA4(sa + 4096 + aRd, ck, af2);                                           \
    LGKMC(6);   /* af+bf0 landed */                                           \
    PRIO1(); mfma_quad<0,0>(acc, af, bf0); PRIO0();                           \
    LGKMC(4);   /* bf1 landed */                                              \
    PRIO1(); mfma_quad<0,1>(acc, af, bf1); PRIO0();                           \
    LGKMC(0);   /* af2 landed */                                              \
    PRIO1(); mfma_quad<1,0>(acc, af2, bf0); PRIO0();                          \
    if (DO_TAIL) { PRIO1(); mfma_quad<1,1>(acc, af2, bf1); PRIO0(); }         \
    WAIT_END;                                                                 \
    if (BAR_END) BARRIER();                                                   \
} while (0)

    TILE(0, 0, 1, WAITV(8), 1, 0);
    #pragma unroll 1
    for (int t = 1; t <= NT - 4; ++t) {
        TILE(t, 1, 1, WAITV(8), 1, 0);
    }
    TILE(NT - 3, 1, 0, WAITV(4), 1, 0);
    TILE(NT - 2, 1, 0, WAITV(0), 1, 0);
    TILE(NT - 1, 1, 0, (void)0,  0, 1);
#undef TILE

    // epilogue: C/D layout col = lane&15, row = lq*4 + reg
    #pragma unroll
    for (int hA = 0; hA < 2; ++hA)
    #pragma unroll
    for (int hB = 0; hB < 2; ++hB)
    #pragma unroll
    for (int n = 0; n < 2; ++n) {
        const int col = (int)bcol + hB * 128 + wc * 32 + n * 16 + fr;
        const float bv = bias[col];
        #pragma unroll
        for (int m = 0; m < 4; ++m) {
            const size_t row0 = (size_t)brow + hA * 128 + wr * 64 + m * 16 + lq * 4;
            #pragma unroll
            for (int r = 0; r < 4; ++r)
                C[(row0 + r) * OUT_DIM + col] = acc[hA][hB][m][n][r] + bv;
        }
    }
}

// ---------------------------------------------------------------------------
extern "C" void kernel_launch(void* const* d_in, const int* in_sizes, int n_in,
                              void* d_out, int out_size, void* d_ws, size_t ws_size,
                              hipStream_t stream)
{
    const float* x        = (const float*)d_in[0];
    const float* norms_p  = (const float*)d_in[1];
    const float* norms_r  = (const float*)d_in[2];
    const float* bias     = (const float*)d_in[3];
    const int*   idx_p    = (const int*)d_in[4];
    const int*   idx_r    = (const int*)d_in[5];
    float*       out      = (float*)d_out;

    // workspace: xb (64 MB bf16 [M][K]) | W (32 MB bf16 [N][K])
    short* xb = (short*)d_ws;
    short* wq = (short*)d_ws + (size_t)M_TOTAL * IN_DIM;

    dequant_kernel<<<(OUT_DIM * NGROUPS) / 4, 256, 0, stream>>>(
        norms_p, norms_r, idx_p, idx_r, wq);

    cast_kernel<<<(int)(((size_t)M_TOTAL * IN_DIM) / (256 * 8)), 256, 0, stream>>>(x, xb);

    gemm_kernel<<<(M_TOTAL / BM) * (OUT_DIM / BN), 512, 0, stream>>>(xb, wq, bias, out);
}

// Round 14
// 278.681 us; speedup vs baseline: 1.0594x; 1.0594x over previous
//
#include <hip/hip_runtime.h>
#include <hip/hip_bf16.h>
#include <stdint.h>

// Problem constants
#define OUT_DIM 4096
#define IN_DIM  4096
#define GROUPSZ 128
#define NGROUPS 32
#define M_TOTAL 8192   // 4 * 2048
#define EPS_Q   1e-12f

// GEMM tiling: 256x256 tile, BK=64, 8 waves (2M x 4N), 16x16x32 MFMA
#define BM 256
#define BN 256
#define BK 64
#define NT (IN_DIM / BK)   // 64 K-tiles

typedef float f32x4   __attribute__((ext_vector_type(4)));
typedef float float4v __attribute__((ext_vector_type(4)));
typedef short bf16x8  __attribute__((ext_vector_type(8)));

static __device__ __forceinline__ short f2bf(float f) {
    union { float f; unsigned u; } v; v.f = f;
    unsigned r = v.u + 0x7fffu + ((v.u >> 16) & 1u);
    return (short)(r >> 16);
}

#define GLOAD16(gp, lp) __builtin_amdgcn_global_load_lds( \
    (const __attribute__((address_space(1))) void*)(gp),  \
    (__attribute__((address_space(3))) void*)(lp), 16, 0, 0)

// ---------------------------------------------------------------------------
// Kernel 1: dequantize W (bf16, [N][K] = B^T layout). One wave per (o, g).
// ---------------------------------------------------------------------------
__global__ __launch_bounds__(256) void dequant_kernel(
    const float* __restrict__ norms_p, const float* __restrict__ norms_r,
    const int* __restrict__ idx_p, const int* __restrict__ idx_r,
    short* __restrict__ W)
{
    const int gid  = (int)((blockIdx.x * 256u + threadIdx.x) >> 6);
    const int lane = threadIdx.x & 63;
    const size_t base = (size_t)gid * GROUPSZ;

    const int ip0 = idx_p[base + lane];
    const int ip1 = idx_p[base + lane + 64];
    const int ir0 = idx_r[base + lane];
    const int ir1 = idx_r[base + lane + 64];

    const float qp0 = -1.f + (2.f / 15.f) * (float)ip0;
    const float qp1 = -1.f + (2.f / 15.f) * (float)ip1;
    const float qr0 = -1.f + (2.f / 3.f)  * (float)ir0;
    const float qr1 = -1.f + (2.f / 3.f)  * (float)ir1;

    float ssp = qp0 * qp0 + qp1 * qp1;
    float ssr = qr0 * qr0 + qr1 * qr1;
    #pragma unroll
    for (int m = 32; m >= 1; m >>= 1) {
        ssp += __shfl_xor(ssp, m);
        ssr += __shfl_xor(ssr, m);
    }
    const float sp = norms_p[gid] / sqrtf(ssp + EPS_Q);
    const float sr = norms_r[gid] / sqrtf(ssr + EPS_Q);

    W[base + lane]      = f2bf(qp0 * sp + qr0 * sr);
    W[base + lane + 64] = f2bf(qp1 * sp + qr1 * sr);
}

// ---------------------------------------------------------------------------
// Kernel 2: x fp32 -> bf16, 8 elems/thread
// ---------------------------------------------------------------------------
__global__ __launch_bounds__(256) void cast_kernel(
    const float* __restrict__ x, short* __restrict__ xb)
{
    const size_t i = ((size_t)blockIdx.x * 256u + threadIdx.x) * 8u;
    float4v a = *(const float4v*)(x + i);
    float4v b = *(const float4v*)(x + i + 4);
    bf16x8 o;
    o[0] = f2bf(a[0]); o[1] = f2bf(a[1]); o[2] = f2bf(a[2]); o[3] = f2bf(a[3]);
    o[4] = f2bf(b[0]); o[5] = f2bf(b[1]); o[6] = f2bf(b[2]); o[7] = f2bf(b[3]);
    *(bf16x8*)(xb + i) = o;
}

// ---------------------------------------------------------------------------
// GEMM helpers (compile-time indexed everywhere — rule #20)
// ---------------------------------------------------------------------------
template<int HA, int HB>
__device__ __forceinline__ void mfma_quad(f32x4 (&acc)[2][2][4][2],
                                          const bf16x8 (&af)[4][2],
                                          const bf16x8 (&bf)[2][2]) {
#pragma unroll
    for (int m = 0; m < 4; ++m)
#pragma unroll
        for (int n = 0; n < 2; ++n)
#pragma unroll
            for (int kh = 0; kh < 2; ++kh)
                acc[HA][HB][m][n] = __builtin_amdgcn_mfma_f32_16x16x32_bf16(
                    af[m][kh], bf[n][kh], acc[HA][HB][m][n], 0, 0, 0);
}

static __device__ __forceinline__ void rd8(const short* base, int ck0, int ck1,
                                           bf16x8 (&f)[4][2]) {
#pragma unroll
    for (int m = 0; m < 4; ++m) {
        f[m][0] = *(const bf16x8*)(base + m * 1024 + ck0);
        f[m][1] = *(const bf16x8*)(base + m * 1024 + ck1);
    }
}

static __device__ __forceinline__ void rd4(const short* base, int ck0, int ck1,
                                           bf16x8 (&f)[2][2]) {
#pragma unroll
    for (int n = 0; n < 2; ++n) {
        f[n][0] = *(const bf16x8*)(base + n * 1024 + ck0);
        f[n][1] = *(const bf16x8*)(base + n * 1024 + ck1);
    }
}

#define BARRIER()  asm volatile("s_barrier" ::: "memory")
#define SCHEDBAR() __builtin_amdgcn_sched_barrier(0)
#define LGKMC(N)   do { asm volatile("s_waitcnt lgkmcnt(" #N ")" ::: "memory"); \
                        SCHEDBAR(); } while (0)
#define WAITV(N)   asm volatile("s_waitcnt vmcnt(" #N ")" ::: "memory")

// ---------------------------------------------------------------------------
// Kernel 3: C[M][N] = A[M][K] @ B[N][K]^T + bias, bf16 in / fp32 out.
// Round-4 skeleton (validated 2-barrier ledger) + DEFERRED-QUAD rotation:
// each tile's quad(1,1) (operands af2/bf1 already in registers) executes at
// the START of the next tile body, overlapping the next tile's exposed
// 12-ds_read batch. Schedule per K-tile t (steady state):
//   rd A0(t)->af(8), B0(t)->bf0(4); stage (t+1)A1; SCHEDBAR
//   [PEND] quad(1,1) of t-1 (af2,bf1 regs — covers the reads)
//   lgkmcnt(0) -> quad(0,0)
//   WAITV(6); BARRIER
//   rd B1(t)->bf1 then A1(t)->af2; stage (t+1)B1
//   lgkmcnt(8) -> quad(0,1); stage (t+2)A0
//   lgkmcnt(0) -> quad(1,0); stage (t+2)B0
//   WAITV(8); BARRIER          [quad(1,1) of t deferred]
// Staging order, vmcnt ledger, barriers identical to round 4 (validated).
// LDS 128 KiB: buf*32768 + {A0:0, A1:8192, B0:16384, B1:24576} shorts.
// Chunk swizzle: LDS chunk = global_chunk ^ (row&7) (both-sides involution).
// ---------------------------------------------------------------------------
__global__ __launch_bounds__(512, 2) void gemm_kernel(
    const short* __restrict__ Ag,  // [M][K] bf16
    const short* __restrict__ Bg,  // [N][K] bf16
    const float* __restrict__ bias,
    float* __restrict__ C)
{
    __shared__ short lds[65536];   // 128 KiB

    const int tid  = threadIdx.x;
    const int lane = tid & 63;
    const int wid  = tid >> 6;     // 0..7
    const int wr   = wid >> 2;     // 0..1 (M)
    const int wc   = wid & 3;      // 0..3 (N)
    const int fr   = lane & 15;
    const int lq   = lane >> 4;    // 0..3

    // bijective XCD swizzle (nwg = 512, divisible by 8)
    const int nwg = gridDim.x;
    const int cpx = nwg >> 3;
    const int wg  = ((int)blockIdx.x & 7) * cpx + ((int)blockIdx.x >> 3);
    const int ntile = wg & 15;              // N/BN = 16
    const int mtile = wg >> 4;              // M/BM = 32
    const uint32_t brow = (uint32_t)mtile * BM;
    const uint32_t bcol = (uint32_t)ntile * BN;

    // staging: slot s (0..1023): row r = s>>3, chunk c = s&7; thread owns
    // s = tid and s = tid+512. global chunk = c ^ (r&7).
    const uint32_t sr_ = (uint32_t)(tid >> 3);
    const uint32_t gc_ = (uint32_t)((tid & 7) ^ ((tid >> 3) & 7));
    const uint32_t aOffB = (brow + sr_) * IN_DIM + gc_ * 8;
    const uint32_t bOffB = (bcol + sr_) * IN_DIM + gc_ * 8;

    auto stage = [&](const short* M, uint32_t baseOff, uint32_t extra, short* dstRegion) {
        GLOAD16(M + baseOff + extra,            dstRegion + tid * 8);
        GLOAD16(M + baseOff + extra + 262144u,  dstRegion + tid * 8 + 4096);
    };

    // fragment read offsets (shorts): row*64 + ((kh*4+kc)^(fr&7))*8
    const int c0  = (lq ^ (fr & 7));
    const int ck0 = c0 * 8;
    const int ck1 = (c0 ^ 4) * 8;
    const int aRd = (wr * 64 + fr) * 64;
    const int bRd = (wc * 32 + fr) * 64;

    f32x4  acc[2][2][4][2] = {};
    bf16x8 af[4][2], af2[4][2], bf0[2][2], bf1[2][2];

    // prologue: (0)A0,(0)B0,(0)A1,(0)B1,(1)A0,(1)B0 = 12 loads
    stage(Ag, aOffB, 0u,            lds);
    stage(Bg, bOffB, 0u,            lds + 16384);
    stage(Ag, aOffB, 524288u,       lds + 8192);
    stage(Bg, bOffB, 524288u,       lds + 24576);
    stage(Ag, aOffB, 64u,           lds + 32768);
    stage(Bg, bOffB, 64u,           lds + 32768 + 16384);
    WAITV(8);          // (0)A0,(0)B0 landed; 8 outstanding
    BARRIER();

#define TILE_BODY(T, PEND, STG0, STG1, STG2, STG3, WAIT_MID, WAIT_END, BAR_END, DO_TAIL) do { \
    short* sb = lds + (((T) & 1) ? 32768 : 0);                                \
    short* ob = lds + (((T) & 1) ? 0 : 32768);                                \
    /* batch 1: A0 -> af, B0 -> bf0 (12 ds_reads), pinned first */            \
    rd8(sb + aRd, ck0, ck1, af);                                              \
    rd4(sb + 16384 + bRd, ck0, ck1, bf0);                                     \
    if (STG0) stage(Ag, aOffB, 524288u + (uint32_t)((T) + 1) * 64u, ob + 8192); \
    SCHEDBAR();                                                               \
    if (PEND) { /* deferred quad(1,1) of T-1: regs only, hides the reads */   \
        __builtin_amdgcn_s_setprio(1); mfma_quad<1,1>(acc, af2, bf1);         \
        __builtin_amdgcn_s_setprio(0);                                        \
    }                                                                         \
    LGKMC(0);                                                                 \
    __builtin_amdgcn_s_setprio(1); mfma_quad<0,0>(acc, af, bf0);              \
    __builtin_amdgcn_s_setprio(0);                                            \
    WAIT_MID;                                                                 \
    BARRIER();                                                                \
    /* batch 2: B1 -> bf1 (oldest), then A1 -> af2 */                         \
    rd4(sb + 24576 + bRd, ck0, ck1, bf1);                                     \
    SCHEDBAR();                                                               \
    rd8(sb + 8192 + aRd, ck0, ck1, af2);                                      \
    if (STG1) stage(Bg, bOffB, 524288u + (uint32_t)((T) + 1) * 64u, ob + 24576); \
    LGKMC(8);   /* bf1 landed; af2 may still be in flight */                  \
    __builtin_amdgcn_s_setprio(1); mfma_quad<0,1>(acc, af, bf1);              \
    __builtin_amdgcn_s_setprio(0);                                            \
    if (STG2) stage(Ag, aOffB, (uint32_t)((T) + 2) * 64u, sb);                \
    LGKMC(0);   /* af2 landed (covered by quad(0,1) issue) */                 \
    __builtin_amdgcn_s_setprio(1); mfma_quad<1,0>(acc, af2, bf0);             \
    __builtin_amdgcn_s_setprio(0);                                            \
    if (STG3) stage(Bg, bOffB, (uint32_t)((T) + 2) * 64u, sb + 16384);        \
    if (DO_TAIL) { /* last tile: its own quad(1,1) inline */                  \
        __builtin_amdgcn_s_setprio(1); mfma_quad<1,1>(acc, af2, bf1);         \
        __builtin_amdgcn_s_setprio(0);                                        \
    }                                                                         \
    WAIT_END;                                                                 \
    if (BAR_END) BARRIER();                                                   \
} while (0)

    // tile 0: no pending quad
    TILE_BODY(0, 0, 1, 1, 1, 1, WAITV(6), WAITV(8), 1, 0);
    #pragma unroll 1
    for (int t = 1; t < NT - 2; ++t) {
        TILE_BODY(t, 1, 1, 1, 1, 1, WAITV(6), WAITV(8), 1, 0);
    }
    TILE_BODY(NT - 2, 1, 1, 1, 0, 0, WAITV(6), WAITV(4), 1, 0);
    TILE_BODY(NT - 1, 1, 0, 0, 0, 0, WAITV(0), (void)0, 0, 1);
#undef TILE_BODY

    // epilogue: C/D layout col = lane&15, row = lq*4 + reg
    #pragma unroll
    for (int hA = 0; hA < 2; ++hA)
    #pragma unroll
    for (int hB = 0; hB < 2; ++hB)
    #pragma unroll
    for (int n = 0; n < 2; ++n) {
        const int col = (int)bcol + hB * 128 + wc * 32 + n * 16 + fr;
        const float bv = bias[col];
        #pragma unroll
        for (int m = 0; m < 4; ++m) {
            const size_t row0 = (size_t)brow + hA * 128 + wr * 64 + m * 16 + lq * 4;
            #pragma unroll
            for (int r = 0; r < 4; ++r)
                C[(row0 + r) * OUT_DIM + col] = acc[hA][hB][m][n][r] + bv;
        }
    }
}

// ---------------------------------------------------------------------------
extern "C" void kernel_launch(void* const* d_in, const int* in_sizes, int n_in,
                              void* d_out, int out_size, void* d_ws, size_t ws_size,
                              hipStream_t stream)
{
    const float* x        = (const float*)d_in[0];
    const float* norms_p  = (const float*)d_in[1];
    const float* norms_r  = (const float*)d_in[2];
    const float* bias     = (const float*)d_in[3];
    const int*   idx_p    = (const int*)d_in[4];
    const int*   idx_r    = (const int*)d_in[5];
    float*       out      = (float*)d_out;

    // workspace: xb (64 MB bf16 [M][K]) | W (32 MB bf16 [N][K])
    short* xb = (short*)d_ws;
    short* wq = (short*)d_ws + (size_t)M_TOTAL * IN_DIM;

    dequant_kernel<<<(OUT_DIM * NGROUPS) / 4, 256, 0, stream>>>(
        norms_p, norms_r, idx_p, idx_r, wq);

    cast_kernel<<<(int)(((size_t)M_TOTAL * IN_DIM) / (256 * 8)), 256, 0, stream>>>(x, xb);

    gemm_kernel<<<(M_TOTAL / BM) * (OUT_DIM / BN), 512, 0, stream>>>(xb, wq, bias, out);
}